// Round 5
// baseline (1516.137 us; speedup 1.0000x reference)
//
#include <hip/hip_runtime.h>
#include <math.h>

#define NPERSEG 30
#define STEPW 15
#define NSEG 3
#define NF 16
#define PATCH 60
#define STRIDE 30
#define NP_ROW 199
#define NBATCH 1024
#define T_LEN 6000
#define NPATCH_TOTAL (NBATCH * NP_ROW)   /* 203776 = 796 * 256 */
#define NBLOCKS (NPATCH_TOTAL / 256)
#define TP 8

// numpy's pairwise f32 sum for n=30 (loops.c.src): 8 partials over 24 elems,
// fixed combine tree, then 6 sequential tail adds.
__device__ __forceinline__ float np_sum30_f32(const float* a) {
    float r[8];
#pragma unroll
    for (int j = 0; j < 8; ++j) r[j] = a[j];
#pragma unroll
    for (int i = 8; i < 24; i += 8)
#pragma unroll
        for (int j = 0; j < 8; ++j) r[j] += a[i + j];
    float res = ((r[0] + r[1]) + (r[2] + r[3])) + ((r[4] + r[5]) + (r[6] + r[7]));
#pragma unroll
    for (int i = 24; i < 30; ++i) res += a[i];
    return res;
}

// numpy pairwise f64 sum for n=16
__device__ __forceinline__ double np_sum16_f64(const double* a) {
    double r[8];
#pragma unroll
    for (int j = 0; j < 8; ++j) r[j] = a[j] + a[8 + j];
    return ((r[0] + r[1]) + (r[2] + r[3])) + ((r[4] + r[5]) + (r[6] + r[7]));
}

__global__ __launch_bounds__(256) void fused_kernel(
    const float* __restrict__ x,
    const float* __restrict__ g_m, const float* __restrict__ b_m,
    const float* __restrict__ g_s, const float* __restrict__ b_s,
    const float* __restrict__ W1, const float* __restrict__ b1,
    const float* __restrict__ W2, const float* __restrict__ b2,
    const float* __restrict__ g_o, const float* __restrict__ b_o,
    float* __restrict__ out)
{
    __shared__ float  Fs[256][22];
    __shared__ float  Hs[TP][128];
    __shared__ float  red1[TP][4], red2[TP][4];
    __shared__ double tc[NPERSEG], ts[NPERSEG];
    __shared__ float  hannf[NPERSEG];     // f32 HANN, cast from f64 (as jnp.asarray(_w, f32))
    __shared__ double WNs;                // 200 * sum(_w_f64^2)

    const int tid = threadIdx.x;
    if (tid < NPERSEG) {
        double ang = (2.0 * M_PI * (double)tid) / 30.0;  // mirrors 2*pi*arange(30)/30
        double c = cos(ang);
        tc[tid] = c;
        ts[tid] = sin(ang);
        hannf[tid] = (float)(0.5 * (1.0 - c));
    }
    __syncthreads();
    if (tid == 0) {
        double s = 0.0;
        for (int n = 0; n < NPERSEG; ++n) {
            double w = 0.5 * (1.0 - cos((2.0 * M_PI * (double)n) / 30.0));
            s += w * w;
        }
        WNs = 200.0 * s;
    }
    __syncthreads();

    // ================= phase 1: one thread = one patch =================
    const int g   = blockIdx.x * 256 + tid;
    const int bb_ = g / NP_ROW;
    const int pi  = g - bb_ * NP_ROW;
    const float* xp = x + (size_t)bb_ * T_LEN + (size_t)pi * STRIDE;

    float pf[PATCH];
#pragma unroll
    for (int n = 0; n < PATCH; ++n) pf[n] = xp[n];

    // ---- morph (f64 continuous; discrete decisions input-exact; zc in f32 literal) ----
    double morph[13];
    {
        double vmax = (double)pf[0], vmin = vmax, vsum = 0.0;
#pragma unroll
        for (int n = 0; n < PATCH; ++n) {
            double v = (double)pf[n];
            vmax = fmax(vmax, v); vmin = fmin(vmin, v); vsum += v;
        }
        double vmean = vsum / 60.0;
        double s2 = 0.0, s3 = 0.0, s4 = 0.0, ssq = 0.0;
#pragma unroll
        for (int n = 0; n < PATCH; ++n) {
            double v = (double)pf[n];
            double c = v - vmean, c2 = c * c;
            s2 += c2; s3 += c2 * c; s4 += c2 * c2;
            ssq += v * v;
        }
        double m2 = s2 / 60.0, m3 = s3 / 60.0, m4 = s4 / 60.0;
        double vstd = sqrt(m2);

        int amax = 0; float aval = fabsf(pf[0]);
#pragma unroll
        for (int n = 1; n < PATCH; ++n) {
            float a = fabsf(pf[n]);
            if (a > aval) { aval = a; amax = n; }
        }
        double peak_loc = (double)((float)amax / 60.0f);

        double dmax = (double)pf[1] - (double)pf[0], dmin = dmax, dabssum = 0.0;
#pragma unroll
        for (int n = 0; n < PATCH - 1; ++n) {
            double d = (double)pf[n + 1] - (double)pf[n];
            dmax = fmax(dmax, d); dmin = fmin(dmin, d); dabssum += fabs(d);
        }
        double dabsmean = dabssum / 59.0;

        int zc = 0;
        {
            float v0 = pf[0] + 1e-10f;
            int prev = (v0 > 0.0f) - (v0 < 0.0f);
#pragma unroll
            for (int n = 1; n < PATCH; ++n) {
                float v = pf[n] + 1e-10f;
                int s = (v > 0.0f) - (v < 0.0f);
                if (s != prev) zc++;
                prev = s;
            }
        }
        double zcf = (double)zc / 60.0;
        double kurt = m4 / (m2 * m2) - 3.0;
        double skew = m3 / (m2 * sqrt(m2));

        morph[0] = vmax;  morph[1] = vmin;  morph[2] = vmax - vmin;
        morph[3] = vmean; morph[4] = vstd;  morph[5] = peak_loc;
        morph[6] = dmax;  morph[7] = dmin;  morph[8] = dabsmean;
        morph[9] = zcf;   morph[10] = ssq;  morph[11] = kurt; morph[12] = skew;
#pragma unroll
        for (int i = 0; i < 13; ++i) if (!isfinite(morph[i])) morph[i] = 0.0;
    }

    // ---- Welch PSD: f32 windowing (numpy-literal), f64 DFT ----
    const double WN = WNs;
    double psd[NF];
#pragma unroll
    for (int k = 0; k < NF; ++k) psd[k] = 0.0;

    for (int s = 0; s < NSEG; ++s) {
        const float* q = pf + s * STEPW;
        float res = np_sum30_f32(q);
        float smean = res / 30.0f;           // f32 division, as np.mean
        float y[NPERSEG];
#pragma unroll
        for (int n = 0; n < NPERSEG; ++n) y[n] = (q[n] - smean) * hannf[n];  // f32 ops
        for (int k = 0; k < NF; ++k) {
            double re = 0.0, im = 0.0;
#pragma unroll
            for (int n = 0; n < NPERSEG; ++n) {
                int idx = (k * n) % NPERSEG;
                double yn = (double)y[n];
                re += yn * tc[idx];
                im += yn * ts[idx];
            }
            double v = re * re + im * im;
            v = v / WN;                               // ref op order: /WIN_NORM
            v = v * ((k == 0 || k == NF - 1) ? 1.0 : 2.0);  // * ONESIDED
            psd[k] += v;                              // sum over segs
        }
    }
#pragma unroll
    for (int k = 0; k < NF; ++k) psd[k] = psd[k] / 3.0;   // .mean(-2)

    // ---- spectral features, f64, literal decisions, NO tie hacks ----
    double total = np_sum16_f64(psd) + 1e-12;
    double invt = 1.0 / total;

    double band1 = psd[1] * invt;
    double band3 = ((psd[2] + psd[3]) + psd[4]) * invt;
    double b4s = 0.0;
#pragma unroll
    for (int k = 5; k <= 14; ++k) b4s += psd[k];
    double band4 = b4s * invt;

    int bk = 0; double bpv = psd[0];
#pragma unroll
    for (int k = 1; k < NF; ++k) if (psd[k] > bpv) { bpv = psd[k]; bk = k; }

    double th = 0.95 * total;
    int ek = 0;
    {
        double acc = 0.0; bool found = false;
#pragma unroll
        for (int k = 0; k < NF; ++k) {
            acc += psd[k];
            if (!found && acc >= th) { ek = k; found = true; }
        }
    }

    double ent = 0.0;
#pragma unroll
    for (int k = 0; k < NF; ++k) {
        double pn = psd[k] * invt;
        ent -= pn * log2(pn + 1e-12);
    }

    double spec[9];
    spec[0] = 0.0;
    spec[1] = band1;
    spec[2] = 0.0;
    spec[3] = band3;
    spec[4] = band4;
    spec[5] = (double)((float)((double)bk * 200.0 / 30.0));  // FREQS is f32
    spec[6] = (double)((float)((double)ek * 200.0 / 30.0));
    spec[7] = ent;
    spec[8] = total;
#pragma unroll
    for (int i = 0; i < 9; ++i) if (!isfinite(spec[i])) spec[i] = 0.0;

    // ---- group layernorms (f64) → Fs (f32) ----
    {
        double mu = 0.0;
#pragma unroll
        for (int i = 0; i < 13; ++i) mu += morph[i];
        mu /= 13.0;
        double var = 0.0;
#pragma unroll
        for (int i = 0; i < 13; ++i) { double d = morph[i] - mu; var += d * d; }
        var /= 13.0;
        double inv = 1.0 / sqrt(var + 1e-5);
#pragma unroll
        for (int i = 0; i < 13; ++i)
            Fs[tid][i] = (float)((morph[i] - mu) * inv * (double)g_m[i] + (double)b_m[i]);
    }
    {
        double mu = 0.0;
#pragma unroll
        for (int i = 0; i < 9; ++i) mu += spec[i];
        mu /= 9.0;
        double var = 0.0;
#pragma unroll
        for (int i = 0; i < 9; ++i) { double d = spec[i] - mu; var += d * d; }
        var /= 9.0;
        double inv = 1.0 / sqrt(var + 1e-5);
#pragma unroll
        for (int i = 0; i < 9; ++i)
            Fs[tid][13 + i] = (float)((spec[i] - mu) * inv * (double)g_s[i] + (double)b_s[i]);
    }
    __syncthreads();

    // ================= phase 2: MLP (f32), 32 groups of TP patches =================
    const int ch = tid;
    const int lane = tid & 63, wv = tid >> 6;
    const float bias2 = b2[ch];
    const float gch = g_o[ch], bch = b_o[ch];
    const long blk0 = (long)blockIdx.x * 256;

    for (int grp = 0; grp < 32; ++grp) {
        const int l0 = grp * TP;

#pragma unroll
        for (int v = 0; v < 4; ++v) {
            int idx = tid + v * 256;
            int pp = idx >> 7, hc = idx & 127;
            float a = b1[hc];
#pragma unroll
            for (int k = 0; k < 22; ++k) a += Fs[l0 + pp][k] * W1[k * 128 + hc];
            Hs[pp][hc] = 0.5f * a * (1.0f + erff(a * 0.70710678118654752440f));
        }
        __syncthreads();

        float acc[TP];
#pragma unroll
        for (int pp = 0; pp < TP; ++pp) acc[pp] = bias2;
        for (int k = 0; k < 128; ++k) {
            float w = W2[k * 256 + ch];
#pragma unroll
            for (int pp = 0; pp < TP; ++pp) acc[pp] += Hs[pp][k] * w;
        }

#pragma unroll
        for (int pp = 0; pp < TP; ++pp) {
            float a = acc[pp], q = acc[pp] * acc[pp];
            for (int off = 32; off; off >>= 1) {
                a += __shfl_xor(a, off);
                q += __shfl_xor(q, off);
            }
            if (lane == 0) { red1[pp][wv] = a; red2[pp][wv] = q; }
        }
        __syncthreads();

#pragma unroll
        for (int pp = 0; pp < TP; ++pp) {
            float a = red1[pp][0] + red1[pp][1] + red1[pp][2] + red1[pp][3];
            float q = red2[pp][0] + red2[pp][1] + red2[pp][2] + red2[pp][3];
            float mu = a * (1.0f / 256.0f);
            float var = q * (1.0f / 256.0f) - mu * mu;
            float inv = rsqrtf(var + 1e-5f);
            out[(blk0 + l0 + pp) * 256 + ch] = (acc[pp] - mu) * inv * gch + bch;
        }
        __syncthreads();
    }
}

extern "C" void kernel_launch(void* const* d_in, const int* in_sizes, int n_in,
                              void* d_out, int out_size, void* d_ws, size_t ws_size,
                              hipStream_t stream) {
    const float* x   = (const float*)d_in[0];
    const float* g_m = (const float*)d_in[1];
    const float* b_m = (const float*)d_in[2];
    const float* g_s = (const float*)d_in[3];
    const float* b_s = (const float*)d_in[4];
    const float* W1  = (const float*)d_in[5];
    const float* b1  = (const float*)d_in[6];
    const float* W2  = (const float*)d_in[7];
    const float* b2  = (const float*)d_in[8];
    const float* g_o = (const float*)d_in[9];
    const float* b_o = (const float*)d_in[10];
    float* out = (float*)d_out;

    fused_kernel<<<NBLOCKS, 256, 0, stream>>>(
        x, g_m, b_m, g_s, b_s, W1, b1, W2, b2, g_o, b_o, out);
}